// Round 1
// baseline (222.740 us; speedup 1.0000x reference)
//
#include <hip/hip_runtime.h>
#include <hip/hip_bf16.h>

typedef unsigned short u16;
typedef __attribute__((ext_vector_type(4))) float f32x4;
typedef __attribute__((ext_vector_type(8))) __bf16 bf16x8;

#define NH 16
#define HD 64
#define HID 1024
#define SS 2048
#define MM 4096

__device__ __forceinline__ u16 f2b(float f) {
  unsigned u = __builtin_bit_cast(unsigned, f);
  u += 0x7fff + ((u >> 16) & 1);   // RNE
  return (u16)(u >> 16);
}

// ---------------- fp32 -> bf16 conversion (vectorized) ----------------
__global__ void cvt4(const float* __restrict__ src, u16* __restrict__ dst, int n4) {
  int i = blockIdx.x * 256 + threadIdx.x;
  if (i >= n4) return;
  float4 v = reinterpret_cast<const float4*>(src)[i];
  ushort4 o;
  o.x = f2b(v.x); o.y = f2b(v.y); o.z = f2b(v.z); o.w = f2b(v.w);
  reinterpret_cast<ushort4*>(dst)[i] = o;
}

// ---------------- fused QKV projection ----------------
// y = x @ W^T + b ; writes q,k as [BH][S][HD] bf16, v transposed [BH][HD][S]
__global__ __launch_bounds__(256)
void gemm_qkv(const u16* __restrict__ xb,
              const u16* __restrict__ wqb, const u16* __restrict__ wkb, const u16* __restrict__ wvb,
              const float* __restrict__ bq, const float* __restrict__ bk, const float* __restrict__ bv,
              u16* __restrict__ qh, u16* __restrict__ kh, u16* __restrict__ vt) {
  const int mt = blockIdx.x;             // 0..31
  const int nt = blockIdx.y;             // 0..23
  const int wi = nt >> 3;                // 0=q 1=k 2=v
  const int n0 = (nt & 7) << 7;
  const int m0 = mt << 7;
  const u16* wb = (wi == 0) ? wqb : (wi == 1) ? wkb : wvb;
  const float* bias = (wi == 0) ? bq : (wi == 1) ? bk : bv;

  __shared__ u16 at[128][40];            // pad 32->40 elems (80B pitch, 16B aligned)
  __shared__ u16 bt[128][40];

  const int tid = threadIdx.x;
  const int wave = tid >> 6;
  const int lane = tid & 63;
  const int wm = (wave >> 1) << 6;       // wave row offset (2x2 wave grid)
  const int wn = (wave & 1) << 6;
  const int lr = lane & 15;
  const int lk = (lane >> 4) << 3;
  const int rb = (lane >> 4) << 2;

  f32x4 acc[4][4] = {};

  for (int k0 = 0; k0 < HID; k0 += 32) {
    __syncthreads();
    #pragma unroll
    for (int s = tid; s < 512; s += 256) {
      const int row = s >> 2, c = (s & 3) << 3;
      *reinterpret_cast<float4*>(&at[row][c]) =
          *reinterpret_cast<const float4*>(&xb[(size_t)(m0 + row) * HID + k0 + c]);
      *reinterpret_cast<float4*>(&bt[row][c]) =
          *reinterpret_cast<const float4*>(&wb[(size_t)(n0 + row) * HID + k0 + c]);
    }
    __syncthreads();
    bf16x8 af[4], bfr[4];
    #pragma unroll
    for (int i = 0; i < 4; i++) {
      af[i]  = *reinterpret_cast<const bf16x8*>(&at[wm + i * 16 + lr][lk]);
      bfr[i] = *reinterpret_cast<const bf16x8*>(&bt[wn + i * 16 + lr][lk]);
    }
    #pragma unroll
    for (int i = 0; i < 4; i++)
      #pragma unroll
      for (int j = 0; j < 4; j++)
        acc[i][j] = __builtin_amdgcn_mfma_f32_16x16x32_bf16(af[i], bfr[j], acc[i][j], 0, 0, 0);
  }

  #pragma unroll
  for (int i = 0; i < 4; i++) {
    #pragma unroll
    for (int j = 0; j < 4; j++) {
      #pragma unroll
      for (int r = 0; r < 4; r++) {
        const int m = m0 + wm + i * 16 + rb + r;
        const int n = n0 + wn + j * 16 + lr;
        const float val = acc[i][j][r] + bias[n];
        const u16 bv16 = f2b(val);
        const int b = m >> 11, s = m & 2047;
        const int h = n >> 6, d = n & 63;
        if (wi == 0)      qh[((size_t)(b * NH + h) * SS + s) * HD + d] = bv16;
        else if (wi == 1) kh[((size_t)(b * NH + h) * SS + s) * HD + d] = bv16;
        else              vt[((size_t)(b * NH + h) * HD + d) * SS + s] = bv16;
      }
    }
  }
}

// ---------------- flash attention ----------------
// grid (32 bh, 16 qtiles), 256 thr. QBLK=128 (32 rows/wave), KVBLK=64.
__global__ __launch_bounds__(256)
void attn(const u16* __restrict__ qh, const u16* __restrict__ kh, const u16* __restrict__ vt,
          const float* __restrict__ mask, u16* __restrict__ ctxb) {
  const int bh = blockIdx.x;
  const int qt = blockIdx.y;
  const int b = bh >> 4;
  const int h = bh & 15;
  const int q0 = qt << 7;

  const int tid = threadIdx.x;
  const int wave = tid >> 6;
  const int lane = tid & 63;
  const int lr = lane & 15;
  const int lk = (lane >> 4) << 3;
  const int rb = (lane >> 4) << 2;

  const u16* qb = qh + (size_t)bh * SS * HD;
  const u16* kb = kh + (size_t)bh * SS * HD;
  const u16* vb = vt + (size_t)bh * HD * SS;
  const float* mrow = mask + (size_t)b * SS;

  __shared__ u16 kt[64][72];    // K tile, padded (144B pitch)
  __shared__ u16 pt[128][72];   // P transpose buffer

  bf16x8 qf[2][2];
  #pragma unroll
  for (int qs = 0; qs < 2; qs++)
    #pragma unroll
    for (int dk = 0; dk < 2; dk++)
      qf[qs][dk] = *reinterpret_cast<const bf16x8*>(
          &qb[(size_t)(q0 + wave * 32 + qs * 16 + lr) * HD + dk * 32 + lk]);

  f32x4 o[2][4] = {};
  float mrun[2][4], lrun[2][4];
  #pragma unroll
  for (int qs = 0; qs < 2; qs++)
    #pragma unroll
    for (int r = 0; r < 4; r++) { mrun[qs][r] = -1e30f; lrun[qs][r] = 0.f; }

  for (int kv0 = 0; kv0 < SS; kv0 += 64) {
    __syncthreads();
    #pragma unroll
    for (int s = tid; s < 512; s += 256) {
      const int row = s >> 3, c = (s & 7) << 3;
      *reinterpret_cast<float4*>(&kt[row][c]) =
          *reinterpret_cast<const float4*>(&kb[(size_t)(kv0 + row) * HD + c]);
    }
    __syncthreads();

    // S = Q K^T  (2 qsub x 4 ksub fragments, K-dim = HD=64 -> 2 MFMA each)
    f32x4 sa[2][4] = {};
    #pragma unroll
    for (int ks = 0; ks < 4; ks++) {
      const bf16x8 kf0 = *reinterpret_cast<const bf16x8*>(&kt[ks * 16 + lr][lk]);
      const bf16x8 kf1 = *reinterpret_cast<const bf16x8*>(&kt[ks * 16 + lr][32 + lk]);
      #pragma unroll
      for (int qs = 0; qs < 2; qs++) {
        sa[qs][ks] = __builtin_amdgcn_mfma_f32_16x16x32_bf16(qf[qs][0], kf0, sa[qs][ks], 0, 0, 0);
        sa[qs][ks] = __builtin_amdgcn_mfma_f32_16x16x32_bf16(qf[qs][1], kf1, sa[qs][ks], 0, 0, 0);
      }
    }

    float mk[4];
    #pragma unroll
    for (int ks = 0; ks < 4; ks++) mk[ks] = mrow[kv0 + ks * 16 + lr];

    #pragma unroll
    for (int qs = 0; qs < 2; qs++) {
      float tmax[4] = {-1e30f, -1e30f, -1e30f, -1e30f};
      #pragma unroll
      for (int ks = 0; ks < 4; ks++)
        #pragma unroll
        for (int r = 0; r < 4; r++) {
          const float v = sa[qs][ks][r] * 0.125f + mk[ks];
          sa[qs][ks][r] = v;
          tmax[r] = fmaxf(tmax[r], v);
        }
      #pragma unroll
      for (int off = 1; off < 16; off <<= 1)
        #pragma unroll
        for (int r = 0; r < 4; r++)
          tmax[r] = fmaxf(tmax[r], __shfl_xor(tmax[r], off, 16));

      float alpha[4], ts[4];
      #pragma unroll
      for (int r = 0; r < 4; r++) {
        const float mnew = fmaxf(mrun[qs][r], tmax[r]);
        alpha[r] = __expf(mrun[qs][r] - mnew);
        mrun[qs][r] = mnew;
        ts[r] = 0.f;
      }
      #pragma unroll
      for (int ks = 0; ks < 4; ks++)
        #pragma unroll
        for (int r = 0; r < 4; r++) {
          const float p = __expf(sa[qs][ks][r] - mrun[qs][r]);
          sa[qs][ks][r] = p;
          ts[r] += p;
        }
      #pragma unroll
      for (int off = 1; off < 16; off <<= 1)
        #pragma unroll
        for (int r = 0; r < 4; r++)
          ts[r] += __shfl_xor(ts[r], off, 16);
      #pragma unroll
      for (int r = 0; r < 4; r++)
        lrun[qs][r] = lrun[qs][r] * alpha[r] + ts[r];
      #pragma unroll
      for (int ds = 0; ds < 4; ds++)
        #pragma unroll
        for (int r = 0; r < 4; r++)
          o[qs][ds][r] *= alpha[r];
      // P -> LDS (bf16), own wave's rows only
      #pragma unroll
      for (int ks = 0; ks < 4; ks++)
        #pragma unroll
        for (int r = 0; r < 4; r++)
          pt[wave * 32 + qs * 16 + rb + r][ks * 16 + lr] = f2b(sa[qs][ks][r]);
    }

    // O += P V   (A from pt, B from transposed V in global)
    bf16x8 pa[2][2];
    #pragma unroll
    for (int qs = 0; qs < 2; qs++)
      #pragma unroll
      for (int ko = 0; ko < 2; ko++)
        pa[qs][ko] = *reinterpret_cast<const bf16x8*>(&pt[wave * 32 + qs * 16 + lr][ko * 32 + lk]);

    #pragma unroll
    for (int ds = 0; ds < 4; ds++)
      #pragma unroll
      for (int ko = 0; ko < 2; ko++) {
        const bf16x8 vf = *reinterpret_cast<const bf16x8*>(
            &vb[(size_t)(ds * 16 + lr) * SS + kv0 + ko * 32 + lk]);
        #pragma unroll
        for (int qs = 0; qs < 2; qs++)
          o[qs][ds] = __builtin_amdgcn_mfma_f32_16x16x32_bf16(pa[qs][ko], vf, o[qs][ds], 0, 0, 0);
      }
  }

  #pragma unroll
  for (int qs = 0; qs < 2; qs++) {
    float inv[4];
    #pragma unroll
    for (int r = 0; r < 4; r++) inv[r] = 1.0f / lrun[qs][r];
    #pragma unroll
    for (int ds = 0; ds < 4; ds++)
      #pragma unroll
      for (int r = 0; r < 4; r++) {
        const int srow = q0 + wave * 32 + qs * 16 + rb + r;
        ctxb[(size_t)(b * SS + srow) * HID + h * HD + ds * 16 + lr] = f2b(o[qs][ds][r] * inv[r]);
      }
  }
}

// ---------------- output projection (fp32 out) ----------------
__global__ __launch_bounds__(256)
void gemm_out(const u16* __restrict__ ab, const u16* __restrict__ wb,
              const float* __restrict__ bias, float* __restrict__ out) {
  const int m0 = blockIdx.x << 7;
  const int n0 = blockIdx.y << 7;

  __shared__ u16 at[128][40];
  __shared__ u16 bt[128][40];

  const int tid = threadIdx.x;
  const int wave = tid >> 6;
  const int lane = tid & 63;
  const int wm = (wave >> 1) << 6;
  const int wn = (wave & 1) << 6;
  const int lr = lane & 15;
  const int lk = (lane >> 4) << 3;
  const int rb = (lane >> 4) << 2;

  f32x4 acc[4][4] = {};

  for (int k0 = 0; k0 < HID; k0 += 32) {
    __syncthreads();
    #pragma unroll
    for (int s = tid; s < 512; s += 256) {
      const int row = s >> 2, c = (s & 3) << 3;
      *reinterpret_cast<float4*>(&at[row][c]) =
          *reinterpret_cast<const float4*>(&ab[(size_t)(m0 + row) * HID + k0 + c]);
      *reinterpret_cast<float4*>(&bt[row][c]) =
          *reinterpret_cast<const float4*>(&wb[(size_t)(n0 + row) * HID + k0 + c]);
    }
    __syncthreads();
    bf16x8 af[4], bfr[4];
    #pragma unroll
    for (int i = 0; i < 4; i++) {
      af[i]  = *reinterpret_cast<const bf16x8*>(&at[wm + i * 16 + lr][lk]);
      bfr[i] = *reinterpret_cast<const bf16x8*>(&bt[wn + i * 16 + lr][lk]);
    }
    #pragma unroll
    for (int i = 0; i < 4; i++)
      #pragma unroll
      for (int j = 0; j < 4; j++)
        acc[i][j] = __builtin_amdgcn_mfma_f32_16x16x32_bf16(af[i], bfr[j], acc[i][j], 0, 0, 0);
  }

  #pragma unroll
  for (int i = 0; i < 4; i++)
    #pragma unroll
    for (int j = 0; j < 4; j++)
      #pragma unroll
      for (int r = 0; r < 4; r++) {
        const int m = m0 + wm + i * 16 + rb + r;
        const int n = n0 + wn + j * 16 + lr;
        out[(size_t)m * HID + n] = acc[i][j][r] + bias[n];
      }
}

extern "C" void kernel_launch(void* const* d_in, const int* in_sizes, int n_in,
                              void* d_out, int out_size, void* d_ws, size_t ws_size,
                              hipStream_t stream) {
  const float* hs   = (const float*)d_in[0];
  const float* mask = (const float*)d_in[1];
  const float* wq   = (const float*)d_in[2];
  const float* bq   = (const float*)d_in[3];
  const float* wk   = (const float*)d_in[4];
  const float* bk   = (const float*)d_in[5];
  const float* wv   = (const float*)d_in[6];
  const float* bv   = (const float*)d_in[7];
  const float* wo   = (const float*)d_in[8];
  const float* bo   = (const float*)d_in[9];
  float* out = (float*)d_out;

  char* ws = (char*)d_ws;
  u16* xb   = (u16*)(ws);                         // 8 MB  [4096][1024]
  u16* ctxb = (u16*)(ws + ((size_t)8  << 20));    // 8 MB  [4096][1024]
  u16* qhb  = (u16*)(ws + ((size_t)16 << 20));    // 8 MB  [32][2048][64]
  u16* khb  = (u16*)(ws + ((size_t)24 << 20));    // 8 MB
  u16* vtb  = (u16*)(ws + ((size_t)32 << 20));    // 8 MB  [32][64][2048]
  u16* wqb  = (u16*)(ws + ((size_t)40 << 20));    // 2 MB each
  u16* wkb  = (u16*)(ws + ((size_t)42 << 20));
  u16* wvb  = (u16*)(ws + ((size_t)44 << 20));
  u16* wob  = (u16*)(ws + ((size_t)46 << 20));

  cvt4<<<4096, 256, 0, stream>>>(hs, xb, MM * HID / 4);
  cvt4<<<1024, 256, 0, stream>>>(wq, wqb, HID * HID / 4);
  cvt4<<<1024, 256, 0, stream>>>(wk, wkb, HID * HID / 4);
  cvt4<<<1024, 256, 0, stream>>>(wv, wvb, HID * HID / 4);
  cvt4<<<1024, 256, 0, stream>>>(wo, wob, HID * HID / 4);

  gemm_qkv<<<dim3(32, 24), 256, 0, stream>>>(xb, wqb, wkb, wvb, bq, bk, bv, qhb, khb, vtb);
  attn<<<dim3(32, 16), 256, 0, stream>>>(qhb, khb, vtb, mask, ctxb);
  gemm_out<<<dim3(32, 8), 256, 0, stream>>>(ctxb, wob, bo, out);
}